// Round 1
// baseline (1304.788 us; speedup 1.0000x reference)
//
#include <hip/hip_runtime.h>
#include <hip/hip_bf16.h>

#define N_TOK 8192
#define DIM   1024
#define HID   4096
#define NEXP  8

using bf16x8 = __attribute__((ext_vector_type(8))) short;
using f32x4  = __attribute__((ext_vector_type(4))) float;

__device__ __forceinline__ void gload_lds16(const void* g, void* l) {
  __builtin_amdgcn_global_load_lds(
      (const __attribute__((address_space(1))) unsigned int*)g,
      (__attribute__((address_space(3))) unsigned int*)l, 16, 0, 0);
}

__device__ __forceinline__ float wredsum(float v) {
#pragma unroll
  for (int off = 32; off > 0; off >>= 1) v += __shfl_xor(v, off, 64);
  return v;
}

__device__ __forceinline__ unsigned short f2bf(float f) {
  __hip_bfloat16 h = __float2bfloat16(f);
  return *reinterpret_cast<unsigned short*>(&h);
}

// ---------------- prep: LayerNorm + confidence + router + top-2 dispatch ----------------
__global__ __launch_bounds__(256) void prep_kernel(
    const float* __restrict__ x, const float* __restrict__ gamma, const float* __restrict__ beta,
    const float* __restrict__ conf_w, const float* __restrict__ conf_b,
    const float* __restrict__ rw, const float* __restrict__ rb,
    __hip_bfloat16* __restrict__ xn, float* __restrict__ out,
    int* __restrict__ counts, int* __restrict__ lists, float* __restrict__ wts) {
  const int t = blockIdx.x;
  const int tid = threadIdx.x;
  const float4 xv = *(const float4*)(x + (size_t)t * DIM + tid * 4);

  float s = xv.x + xv.y + xv.z + xv.w;
  float s2 = xv.x * xv.x + xv.y * xv.y + xv.z * xv.z + xv.w * xv.w;
  s = wredsum(s);
  s2 = wredsum(s2);

  __shared__ float red[2][4];
  __shared__ float bc[2];
  const int wid = tid >> 6, lane = tid & 63;
  if (lane == 0) { red[0][wid] = s; red[1][wid] = s2; }
  __syncthreads();
  if (tid == 0) {
    float S = red[0][0] + red[0][1] + red[0][2] + red[0][3];
    float S2 = red[1][0] + red[1][1] + red[1][2] + red[1][3];
    float mu = S * (1.f / DIM);
    float var = S2 * (1.f / DIM) - mu * mu;
    bc[0] = mu;
    bc[1] = rsqrtf(var + 1e-5f);
  }
  __syncthreads();
  const float mu = bc[0], inv = bc[1];

  const float4 g4 = *(const float4*)(gamma + tid * 4);
  const float4 b4 = *(const float4*)(beta + tid * 4);
  float xn0 = (xv.x - mu) * inv * g4.x + b4.x;
  float xn1 = (xv.y - mu) * inv * g4.y + b4.y;
  float xn2 = (xv.z - mu) * inv * g4.z + b4.z;
  float xn3 = (xv.w - mu) * inv * g4.w + b4.w;

  ushort4 st;
  st.x = f2bf(xn0); st.y = f2bf(xn1); st.z = f2bf(xn2); st.w = f2bf(xn3);
  *(ushort4*)((unsigned short*)xn + (size_t)t * DIM + tid * 4) = st;

  // out0 initialized to x (residual); out2 = x passthrough
  *(float4*)(out + (size_t)t * DIM + tid * 4) = xv;
  *(float4*)(out + (size_t)N_TOK * DIM + N_TOK + (size_t)t * DIM + tid * 4) = xv;

  float p[9];
#pragma unroll
  for (int e = 0; e < 9; e++) p[e] = 0.f;
  const float xnv[4] = {xn0, xn1, xn2, xn3};
#pragma unroll
  for (int j = 0; j < 4; j++) {
    const int d = tid * 4 + j;
    const float v = xnv[j];
    p[8] += v * conf_w[d];
    const float4 r0 = *(const float4*)(rw + d * 8);
    const float4 r1 = *(const float4*)(rw + d * 8 + 4);
    p[0] += v * r0.x; p[1] += v * r0.y; p[2] += v * r0.z; p[3] += v * r0.w;
    p[4] += v * r1.x; p[5] += v * r1.y; p[6] += v * r1.z; p[7] += v * r1.w;
  }
#pragma unroll
  for (int e = 0; e < 9; e++) p[e] = wredsum(p[e]);
  __shared__ float pr[4][9];
  if (lane == 0) {
#pragma unroll
    for (int e = 0; e < 9; e++) pr[wid][e] = p[e];
  }
  __syncthreads();
  if (tid == 0) {
    float L[8];
#pragma unroll
    for (int e = 0; e < 8; e++) L[e] = pr[0][e] + pr[1][e] + pr[2][e] + pr[3][e] + rb[e];
    float cl = pr[0][8] + pr[1][8] + pr[2][8] + pr[3][8] + conf_b[0];
    out[(size_t)N_TOK * DIM + t] = 1.f / (1.f + expf(-cl));

    float mx = L[0];
#pragma unroll
    for (int e = 1; e < 8; e++) mx = fmaxf(mx, L[e]);
    float pe[8];
#pragma unroll
    for (int e = 0; e < 8; e++) pe[e] = expf(L[e] - mx);
    int i0 = 0; float v0 = pe[0];
#pragma unroll
    for (int e = 1; e < 8; e++) if (pe[e] > v0) { v0 = pe[e]; i0 = e; }
    int i1 = -1; float v1 = -1.f;
#pragma unroll
    for (int e = 0; e < 8; e++) if (e != i0 && pe[e] > v1) { v1 = pe[e]; i1 = e; }
    const float wsum = v0 + v1;
    const float w0 = v0 / wsum, w1 = v1 / wsum;
    int p0 = atomicAdd(&counts[i0], 1);
    lists[i0 * N_TOK + p0] = t; wts[i0 * N_TOK + p0] = w0;
    int p1 = atomicAdd(&counts[i1], 1);
    lists[i1 * N_TOK + p1] = t; wts[i1 * N_TOK + p1] = w1;
  }
}

// ---------------- transpose + cast fp32[R][C] -> bf16[C][R] ----------------
__global__ __launch_bounds__(256) void transpose_cast(
    const float* __restrict__ src, __hip_bfloat16* __restrict__ dst, int R, int C) {
  __shared__ float tile[32][33];
  const int c0 = blockIdx.x * 32, r0 = blockIdx.y * 32;
  const int tx = threadIdx.x, ty = threadIdx.y;  // 32 x 8
#pragma unroll
  for (int k = 0; k < 4; k++)
    tile[ty + 8 * k][tx] = src[(size_t)(r0 + ty + 8 * k) * C + c0 + tx];
  __syncthreads();
#pragma unroll
  for (int k = 0; k < 4; k++)
    dst[(size_t)(c0 + ty + 8 * k) * R + r0 + tx] = __float2bfloat16(tile[tx][ty + 8 * k]);
}

// ---------------- GEMM1: h = relu(gather(xn) @ w1t^T + b1), h stored bf16 ----------------
__global__ __launch_bounds__(256) void gemm1_kernel(
    const __hip_bfloat16* __restrict__ xn, const __hip_bfloat16* __restrict__ w1t,
    const float* __restrict__ bias, const int* __restrict__ list,
    const int* __restrict__ cntp, __hip_bfloat16* __restrict__ hbuf) {
  const int cnt = *cntp;
  const int rt = blockIdx.y;
  if (rt * 128 >= cnt) return;
  const int ct = blockIdx.x;
  __shared__ short As[128 * 32];
  __shared__ short Bs[128 * 32];
  __shared__ int rowtok[128];
  const int tid = threadIdx.x;
  if (tid < 128) {
    int pos = rt * 128 + tid;
    rowtok[tid] = list[pos < cnt ? pos : 0];
  }
  f32x4 acc[4][4] = {};
  const int lane = tid & 63;
  const int wrow = ((tid >> 6) >> 1) * 64;
  const int wcol = ((tid >> 6) & 1) * 64;
  const int lr = lane & 15;
  const int lk = (lane >> 4) * 8;
  const int ldsbase = (tid & ~63) * 8;  // wave-uniform element base (8 shorts per lane slot)

  for (int k0 = 0; k0 < DIM; k0 += 32) {
    __syncthreads();
#pragma unroll
    for (int it = 0; it < 2; ++it) {
      const int idx = it * 256 + tid;
      const int row = idx >> 2;
      const int kq = (idx & 3) << 3;
      gload_lds16(xn + (size_t)rowtok[row] * DIM + k0 + kq, &As[it * 2048 + ldsbase]);
      gload_lds16(w1t + (size_t)(ct * 128 + row) * DIM + k0 + kq, &Bs[it * 2048 + ldsbase]);
    }
    __syncthreads();
    bf16x8 a[4], b[4];
#pragma unroll
    for (int m = 0; m < 4; m++) a[m] = *(const bf16x8*)&As[(wrow + m * 16 + lr) * 32 + lk];
#pragma unroll
    for (int n = 0; n < 4; n++) b[n] = *(const bf16x8*)&Bs[(wcol + n * 16 + lr) * 32 + lk];
#pragma unroll
    for (int m = 0; m < 4; m++)
#pragma unroll
      for (int n = 0; n < 4; n++)
        acc[m][n] = __builtin_amdgcn_mfma_f32_16x16x32_bf16(a[m], b[n], acc[m][n], 0, 0, 0);
  }

#pragma unroll
  for (int n = 0; n < 4; n++) {
    const int col = ct * 128 + wcol + n * 16 + lr;
    const float bv = bias[col];
#pragma unroll
    for (int m = 0; m < 4; m++) {
      f32x4 v = acc[m][n];
#pragma unroll
      for (int j = 0; j < 4; j++) {
        const int rowi = wrow + m * 16 + (lane >> 4) * 4 + j;
        const int pos = rt * 128 + rowi;
        hbuf[(size_t)pos * HID + col] = __float2bfloat16(fmaxf(v[j] + bv, 0.f));
      }
    }
  }
}

// ---------------- GEMM2: out[tok] += w * (h @ w2t^T + b2) ----------------
__global__ __launch_bounds__(256) void gemm2_kernel(
    const __hip_bfloat16* __restrict__ hbuf, const __hip_bfloat16* __restrict__ w2t,
    const float* __restrict__ bias, const int* __restrict__ list,
    const float* __restrict__ wvals, const int* __restrict__ cntp,
    float* __restrict__ out) {
  const int cnt = *cntp;
  const int rt = blockIdx.y;
  if (rt * 128 >= cnt) return;
  const int ct = blockIdx.x;
  __shared__ short As[128 * 32];
  __shared__ short Bs[128 * 32];
  __shared__ int rowtok[128];
  __shared__ float roww[128];
  const int tid = threadIdx.x;
  if (tid < 128) {
    int pos = rt * 128 + tid;
    bool valid = pos < cnt;
    rowtok[tid] = valid ? list[pos] : -1;
    roww[tid] = valid ? wvals[pos] : 0.f;
  }
  f32x4 acc[4][4] = {};
  const int lane = tid & 63;
  const int wrow = ((tid >> 6) >> 1) * 64;
  const int wcol = ((tid >> 6) & 1) * 64;
  const int lr = lane & 15;
  const int lk = (lane >> 4) * 8;
  const int ldsbase = (tid & ~63) * 8;

  for (int k0 = 0; k0 < HID; k0 += 32) {
    __syncthreads();
#pragma unroll
    for (int it = 0; it < 2; ++it) {
      const int idx = it * 256 + tid;
      const int row = idx >> 2;
      const int kq = (idx & 3) << 3;
      gload_lds16(hbuf + (size_t)(rt * 128 + row) * HID + k0 + kq, &As[it * 2048 + ldsbase]);
      gload_lds16(w2t + (size_t)(ct * 128 + row) * HID + k0 + kq, &Bs[it * 2048 + ldsbase]);
    }
    __syncthreads();
    bf16x8 a[4], b[4];
#pragma unroll
    for (int m = 0; m < 4; m++) a[m] = *(const bf16x8*)&As[(wrow + m * 16 + lr) * 32 + lk];
#pragma unroll
    for (int n = 0; n < 4; n++) b[n] = *(const bf16x8*)&Bs[(wcol + n * 16 + lr) * 32 + lk];
#pragma unroll
    for (int m = 0; m < 4; m++)
#pragma unroll
      for (int n = 0; n < 4; n++)
        acc[m][n] = __builtin_amdgcn_mfma_f32_16x16x32_bf16(a[m], b[n], acc[m][n], 0, 0, 0);
  }

#pragma unroll
  for (int n = 0; n < 4; n++) {
    const int col = ct * 128 + wcol + n * 16 + lr;
    const float bv = bias[col];
#pragma unroll
    for (int m = 0; m < 4; m++) {
      f32x4 v = acc[m][n];
#pragma unroll
      for (int j = 0; j < 4; j++) {
        const int rowi = wrow + m * 16 + (lane >> 4) * 4 + j;
        const int tok = rowtok[rowi];
        if (tok >= 0) {
          float* pptr = out + (size_t)tok * DIM + col;
          *pptr += roww[rowi] * (v[j] + bv);
        }
      }
    }
  }
}

extern "C" void kernel_launch(void* const* d_in, const int* in_sizes, int n_in,
                              void* d_out, int out_size, void* d_ws, size_t ws_size,
                              hipStream_t stream) {
  (void)in_sizes; (void)n_in; (void)out_size; (void)ws_size;
  const float* x      = (const float*)d_in[0];
  const float* gamma  = (const float*)d_in[1];
  const float* beta   = (const float*)d_in[2];
  const float* conf_w = (const float*)d_in[3];
  const float* conf_b = (const float*)d_in[4];
  const float* rw     = (const float*)d_in[5];
  const float* rb     = (const float*)d_in[6];
  const float* w1     = (const float*)d_in[7];
  const float* b1     = (const float*)d_in[8];
  const float* w2     = (const float*)d_in[9];
  const float* b2     = (const float*)d_in[10];
  float* out = (float*)d_out;

  char* w = (char*)d_ws;
  __hip_bfloat16* xn   = (__hip_bfloat16*)w; w += (size_t)N_TOK * DIM * 2;   // 16 MB
  __hip_bfloat16* hbuf = (__hip_bfloat16*)w; w += (size_t)N_TOK * HID * 2;   // 64 MB
  __hip_bfloat16* wt   = (__hip_bfloat16*)w; w += (size_t)DIM * HID * 2;     // 8 MB
  int*   lists  = (int*)w;   w += (size_t)NEXP * N_TOK * 4;
  float* wts    = (float*)w; w += (size_t)NEXP * N_TOK * 4;
  int*   counts = (int*)w;   w += 256;

  hipMemsetAsync(counts, 0, NEXP * sizeof(int), stream);
  prep_kernel<<<N_TOK, 256, 0, stream>>>(x, gamma, beta, conf_w, conf_b, rw, rb,
                                         xn, out, counts, lists, wts);
  for (int e = 0; e < NEXP; e++) {
    transpose_cast<<<dim3(HID / 32, DIM / 32), dim3(32, 8), 0, stream>>>(
        w1 + (size_t)e * DIM * HID, wt, DIM, HID);
    gemm1_kernel<<<dim3(HID / 128, N_TOK / 128), 256, 0, stream>>>(
        xn, wt, b1 + (size_t)e * HID, lists + e * N_TOK, counts + e, hbuf);
    transpose_cast<<<dim3(DIM / 32, HID / 32), dim3(32, 8), 0, stream>>>(
        w2 + (size_t)e * HID * DIM, wt, HID, DIM);
    gemm2_kernel<<<dim3(DIM / 128, N_TOK / 128), 256, 0, stream>>>(
        hbuf, wt, b2 + (size_t)e * DIM, lists + e * N_TOK, wts + e * N_TOK, counts + e, out);
  }
}

// Round 2
// 770.423 us; speedup vs baseline: 1.6936x; 1.6936x over previous
//
#include <hip/hip_runtime.h>
#include <hip/hip_bf16.h>

#define N_TOK 8192
#define DIM   1024
#define HID   4096
#define NEXP  8
#define CSTR  64   // counts stride in ints (256B lines -> no atomic line sharing)

using bf16x8 = __attribute__((ext_vector_type(8))) short;
using f32x4  = __attribute__((ext_vector_type(4))) float;

__device__ __forceinline__ void gload_lds16(const void* g, void* l) {
  __builtin_amdgcn_global_load_lds(
      (const __attribute__((address_space(1))) unsigned int*)g,
      (__attribute__((address_space(3))) unsigned int*)l, 16, 0, 0);
}

__device__ __forceinline__ float wredsum(float v) {
#pragma unroll
  for (int off = 32; off > 0; off >>= 1) v += __shfl_xor(v, off, 64);
  return v;
}

__device__ __forceinline__ unsigned short f2bf(float f) {
  __hip_bfloat16 h = __float2bfloat16(f);
  return *reinterpret_cast<unsigned short*>(&h);
}

// ---------------- prep: LN + confidence + router + top-2 dispatch (1 wave / token) ----------------
__global__ __launch_bounds__(256) void prep_kernel(
    const float* __restrict__ x, const float* __restrict__ gamma, const float* __restrict__ beta,
    const float* __restrict__ conf_w, const float* __restrict__ conf_b,
    const float* __restrict__ rw, const float* __restrict__ rb,
    __hip_bfloat16* __restrict__ xn, float* __restrict__ out,
    int* __restrict__ counts, int* __restrict__ lists, float* __restrict__ wts) {
  const int t = blockIdx.x * 4 + (threadIdx.x >> 6);
  const int lane = threadIdx.x & 63;
  const float* xr = x + (size_t)t * DIM;

  float4 xv[4];
#pragma unroll
  for (int q = 0; q < 4; q++) xv[q] = *(const float4*)(xr + q * 256 + lane * 4);

  float s = 0.f, s2 = 0.f;
#pragma unroll
  for (int q = 0; q < 4; q++) {
    s  += xv[q].x + xv[q].y + xv[q].z + xv[q].w;
    s2 += xv[q].x * xv[q].x + xv[q].y * xv[q].y + xv[q].z * xv[q].z + xv[q].w * xv[q].w;
  }
  s = wredsum(s); s2 = wredsum(s2);
  const float mu  = s * (1.f / DIM);
  const float inv = rsqrtf(s2 * (1.f / DIM) - mu * mu + 1e-5f);

  float p[9];
#pragma unroll
  for (int e = 0; e < 9; e++) p[e] = 0.f;

#pragma unroll
  for (int q = 0; q < 4; q++) {
    const int d0 = q * 256 + lane * 4;
    const float4 g4 = *(const float4*)(gamma + d0);
    const float4 b4 = *(const float4*)(beta + d0);
    float v0 = (xv[q].x - mu) * inv * g4.x + b4.x;
    float v1 = (xv[q].y - mu) * inv * g4.y + b4.y;
    float v2 = (xv[q].z - mu) * inv * g4.z + b4.z;
    float v3 = (xv[q].w - mu) * inv * g4.w + b4.w;

    ushort4 st; st.x = f2bf(v0); st.y = f2bf(v1); st.z = f2bf(v2); st.w = f2bf(v3);
    *(ushort4*)((unsigned short*)xn + (size_t)t * DIM + d0) = st;
    *(float4*)(out + (size_t)t * DIM + d0) = xv[q];                                   // residual init
    *(float4*)(out + (size_t)N_TOK * DIM + N_TOK + (size_t)t * DIM + d0) = xv[q];     // x passthrough

    const float vv[4] = {v0, v1, v2, v3};
#pragma unroll
    for (int j = 0; j < 4; j++) {
      const int d = d0 + j;
      const float v = vv[j];
      p[8] += v * conf_w[d];
      const float4 r0 = *(const float4*)(rw + d * 8);
      const float4 r1 = *(const float4*)(rw + d * 8 + 4);
      p[0] += v * r0.x; p[1] += v * r0.y; p[2] += v * r0.z; p[3] += v * r0.w;
      p[4] += v * r1.x; p[5] += v * r1.y; p[6] += v * r1.z; p[7] += v * r1.w;
    }
  }
#pragma unroll
  for (int e = 0; e < 9; e++) p[e] = wredsum(p[e]);

  if (lane == 0) {
    float L[8];
#pragma unroll
    for (int e = 0; e < 8; e++) L[e] = p[e] + rb[e];
    const float cl = p[8] + conf_b[0];
    out[(size_t)N_TOK * DIM + t] = 1.f / (1.f + expf(-cl));

    float mx = L[0];
#pragma unroll
    for (int e = 1; e < 8; e++) mx = fmaxf(mx, L[e]);
    float pe[8];
#pragma unroll
    for (int e = 0; e < 8; e++) pe[e] = expf(L[e] - mx);
    int i0 = 0; float v0 = pe[0];
#pragma unroll
    for (int e = 1; e < 8; e++) if (pe[e] > v0) { v0 = pe[e]; i0 = e; }
    int i1 = -1; float v1 = -1.f;
#pragma unroll
    for (int e = 0; e < 8; e++) if (e != i0 && pe[e] > v1) { v1 = pe[e]; i1 = e; }
    const float wsum = v0 + v1;
    const float w0 = v0 / wsum, w1 = v1 / wsum;
    int p0 = atomicAdd(&counts[i0 * CSTR], 1);
    lists[i0 * N_TOK + p0] = t; wts[i0 * N_TOK + p0] = w0;
    int p1 = atomicAdd(&counts[i1 * CSTR], 1);
    lists[i1 * N_TOK + p1] = t; wts[i1 * N_TOK + p1] = w1;
  }
}

// ---------------- exclusive prefix sum of counts -> bases ----------------
__global__ void bases_kernel(const int* __restrict__ counts, int* __restrict__ bases) {
  if (threadIdx.x == 0) {
    int s = 0;
#pragma unroll
    for (int e = 0; e < NEXP; e++) { bases[e] = s; s += counts[e * CSTR]; }
  }
}

// ---------------- transpose + cast fp32[R][C] -> bf16[C][R], 64x64 tiles, z = matrix ----------------
__global__ __launch_bounds__(256) void transpose_cast64(
    const float* __restrict__ src0, __hip_bfloat16* __restrict__ dst0, int R, int C) {
  __shared__ float tile[64][65];
  const size_t msz = (size_t)R * C;
  const float* src = src0 + blockIdx.z * msz;
  __hip_bfloat16* dst = dst0 + blockIdx.z * msz;
  const int c0 = blockIdx.x * 64, r0 = blockIdx.y * 64;
  const int tid = threadIdx.x;
  const int tx = tid & 15, ty = tid >> 4;
#pragma unroll
  for (int k = 0; k < 4; k++) {
    const int row = ty + k * 16;
    const float4 v = *(const float4*)(src + (size_t)(r0 + row) * C + c0 + tx * 4);
    tile[row][tx * 4 + 0] = v.x; tile[row][tx * 4 + 1] = v.y;
    tile[row][tx * 4 + 2] = v.z; tile[row][tx * 4 + 3] = v.w;
  }
  __syncthreads();
#pragma unroll
  for (int k = 0; k < 4; k++) {
    const int orow = ty + k * 16;  // output row = source col
    ushort4 st;
    st.x = f2bf(tile[tx * 4 + 0][orow]);
    st.y = f2bf(tile[tx * 4 + 1][orow]);
    st.z = f2bf(tile[tx * 4 + 2][orow]);
    st.w = f2bf(tile[tx * 4 + 3][orow]);
    *(ushort4*)((unsigned short*)dst + (size_t)(c0 + orow) * R + r0 + tx * 4) = st;
  }
}

// ---------------- GEMM1: hbuf[base+pos] = relu(gather(xn) @ w1t^T + b1) ----------------
__global__ __launch_bounds__(256) void gemm1_kernel(
    const __hip_bfloat16* __restrict__ xn, const __hip_bfloat16* __restrict__ w1t_b,
    const float* __restrict__ b1, const int* __restrict__ lists,
    const int* __restrict__ counts, const int* __restrict__ bases,
    __hip_bfloat16* __restrict__ hbuf, const int e0) {
  const int e = e0 + (int)(blockIdx.y >> 6);
  const int rt = blockIdx.y & 63;
  const int cnt = counts[e * CSTR];
  if (rt * 128 >= cnt) return;
  const int hbase = bases[e];
  const int ct = blockIdx.x;
  const int* list = lists + e * N_TOK;
  const __hip_bfloat16* w1t = w1t_b + (size_t)(e - e0) * DIM * HID;

  __shared__ short As[128 * 32];
  __shared__ short Bs[128 * 32];
  __shared__ int rowtok[128];
  const int tid = threadIdx.x;
  if (tid < 128) {
    int pos = rt * 128 + tid;
    rowtok[tid] = list[pos < cnt ? pos : 0];
  }
  f32x4 acc[4][4] = {};
  const int lane = tid & 63;
  const int wrow = ((tid >> 6) >> 1) * 64;
  const int wcol = ((tid >> 6) & 1) * 64;
  const int lr = lane & 15;
  const int lk = (lane >> 4) * 8;
  const int ldsbase = (tid & ~63) * 8;

  for (int k0 = 0; k0 < DIM; k0 += 32) {
    __syncthreads();
#pragma unroll
    for (int it = 0; it < 2; ++it) {
      const int idx = it * 256 + tid;
      const int row = idx >> 2;
      const int kq = (idx & 3) << 3;
      gload_lds16(xn + (size_t)rowtok[row] * DIM + k0 + kq, &As[it * 2048 + ldsbase]);
      gload_lds16(w1t + (size_t)(ct * 128 + row) * DIM + k0 + kq, &Bs[it * 2048 + ldsbase]);
    }
    __syncthreads();
    bf16x8 a[4], b[4];
#pragma unroll
    for (int m = 0; m < 4; m++) a[m] = *(const bf16x8*)&As[(wrow + m * 16 + lr) * 32 + lk];
#pragma unroll
    for (int n = 0; n < 4; n++) b[n] = *(const bf16x8*)&Bs[(wcol + n * 16 + lr) * 32 + lk];
#pragma unroll
    for (int m = 0; m < 4; m++)
#pragma unroll
      for (int n = 0; n < 4; n++)
        acc[m][n] = __builtin_amdgcn_mfma_f32_16x16x32_bf16(a[m], b[n], acc[m][n], 0, 0, 0);
  }

#pragma unroll
  for (int n = 0; n < 4; n++) {
    const int col = ct * 128 + wcol + n * 16 + lr;
    const float bv = b1[e * HID + col];
#pragma unroll
    for (int m = 0; m < 4; m++) {
      f32x4 v = acc[m][n];
#pragma unroll
      for (int j = 0; j < 4; j++) {
        const int rowi = wrow + m * 16 + (lane >> 4) * 4 + j;
        const int pos = rt * 128 + rowi;
        if (pos < cnt)
          hbuf[(size_t)(hbase + pos) * HID + col] = __float2bfloat16(fmaxf(v[j] + bv, 0.f));
      }
    }
  }
}

// ---------------- GEMM2: out[tok] += w * (hbuf @ w2t^T + b2) via f32 atomics ----------------
__global__ __launch_bounds__(256) void gemm2_kernel(
    const __hip_bfloat16* __restrict__ hbuf, const __hip_bfloat16* __restrict__ w2t_b,
    const float* __restrict__ b2, const int* __restrict__ lists,
    const float* __restrict__ wts, const int* __restrict__ counts,
    const int* __restrict__ bases, float* __restrict__ out, const int e0) {
  const int e = e0 + (int)(blockIdx.y >> 6);
  const int rt = blockIdx.y & 63;
  const int cnt = counts[e * CSTR];
  if (rt * 128 >= cnt) return;
  const int hbase = bases[e];
  const int ct = blockIdx.x;
  const __hip_bfloat16* w2t = w2t_b + (size_t)(e - e0) * DIM * HID;

  __shared__ short As[128 * 32];
  __shared__ short Bs[128 * 32];
  __shared__ int rowtok[128];
  __shared__ float roww[128];
  const int tid = threadIdx.x;
  if (tid < 128) {
    int pos = rt * 128 + tid;
    bool valid = pos < cnt;
    rowtok[tid] = valid ? lists[e * N_TOK + pos] : -1;
    roww[tid]  = valid ? wts[e * N_TOK + pos] : 0.f;
  }
  f32x4 acc[4][4] = {};
  const int lane = tid & 63;
  const int wrow = ((tid >> 6) >> 1) * 64;
  const int wcol = ((tid >> 6) & 1) * 64;
  const int lr = lane & 15;
  const int lk = (lane >> 4) * 8;
  const int ldsbase = (tid & ~63) * 8;

  for (int k0 = 0; k0 < HID; k0 += 32) {
    __syncthreads();
#pragma unroll
    for (int it = 0; it < 2; ++it) {
      const int idx = it * 256 + tid;
      const int row = idx >> 2;
      const int kq = (idx & 3) << 3;
      gload_lds16(hbuf + (size_t)(hbase + rt * 128 + row) * HID + k0 + kq, &As[it * 2048 + ldsbase]);
      gload_lds16(w2t + (size_t)(ct * 128 + row) * HID + k0 + kq, &Bs[it * 2048 + ldsbase]);
    }
    __syncthreads();
    bf16x8 a[4], b[4];
#pragma unroll
    for (int m = 0; m < 4; m++) a[m] = *(const bf16x8*)&As[(wrow + m * 16 + lr) * 32 + lk];
#pragma unroll
    for (int n = 0; n < 4; n++) b[n] = *(const bf16x8*)&Bs[(wcol + n * 16 + lr) * 32 + lk];
#pragma unroll
    for (int m = 0; m < 4; m++)
#pragma unroll
      for (int n = 0; n < 4; n++)
        acc[m][n] = __builtin_amdgcn_mfma_f32_16x16x32_bf16(a[m], b[n], acc[m][n], 0, 0, 0);
  }

#pragma unroll
  for (int n = 0; n < 4; n++) {
    const int col = ct * 128 + wcol + n * 16 + lr;
    const float bv = b2[e * DIM + col];
#pragma unroll
    for (int m = 0; m < 4; m++) {
      f32x4 v = acc[m][n];
#pragma unroll
      for (int j = 0; j < 4; j++) {
        const int rowi = wrow + m * 16 + (lane >> 4) * 4 + j;
        const int tok = rowtok[rowi];
        if (tok >= 0)
          unsafeAtomicAdd(out + (size_t)tok * DIM + col, roww[rowi] * (v[j] + bv));
      }
    }
  }
}

extern "C" void kernel_launch(void* const* d_in, const int* in_sizes, int n_in,
                              void* d_out, int out_size, void* d_ws, size_t ws_size,
                              hipStream_t stream) {
  (void)in_sizes; (void)n_in; (void)out_size;
  const float* x      = (const float*)d_in[0];
  const float* gamma  = (const float*)d_in[1];
  const float* beta   = (const float*)d_in[2];
  const float* conf_w = (const float*)d_in[3];
  const float* conf_b = (const float*)d_in[4];
  const float* rw     = (const float*)d_in[5];
  const float* rb     = (const float*)d_in[6];
  const float* w1     = (const float*)d_in[7];
  const float* b1     = (const float*)d_in[8];
  const float* w2     = (const float*)d_in[9];
  const float* b2     = (const float*)d_in[10];
  float* out = (float*)d_out;

  char* w = (char*)d_ws;
  auto alloc = [&](size_t bytes) { char* p = w; w += (bytes + 255) & ~255ULL; return p; };

  __hip_bfloat16* xn = (__hip_bfloat16*)alloc((size_t)N_TOK * DIM * 2);
  int*   lists  = (int*)alloc((size_t)NEXP * N_TOK * 4);
  float* wtsb   = (float*)alloc((size_t)NEXP * N_TOK * 4);
  int*   counts = (int*)alloc(NEXP * CSTR * 4);
  int*   bases  = (int*)alloc(256);
  size_t common = (size_t)(w - (char*)d_ws);

  const size_t hbufA = (size_t)(2 * N_TOK + 128) * HID * 2;   // assignment-compact + tail pad
  const size_t wtA   = (size_t)NEXP * DIM * HID * 2;          // per weight set
  const bool planA = ws_size >= common + hbufA + 2 * wtA + 4096;

  hipMemsetAsync(counts, 0, NEXP * CSTR * 4, stream);
  prep_kernel<<<N_TOK / 4, 256, 0, stream>>>(x, gamma, beta, conf_w, conf_b, rw, rb,
                                             xn, out, counts, lists, wtsb);

  if (planA) {
    __hip_bfloat16* hbuf = (__hip_bfloat16*)alloc(hbufA);
    __hip_bfloat16* w1t  = (__hip_bfloat16*)alloc(wtA);
    __hip_bfloat16* w2t  = (__hip_bfloat16*)alloc(wtA);
    bases_kernel<<<1, 64, 0, stream>>>(counts, bases);
    transpose_cast64<<<dim3(HID / 64, DIM / 64, NEXP), 256, 0, stream>>>(w1, w1t, DIM, HID);
    transpose_cast64<<<dim3(DIM / 64, HID / 64, NEXP), 256, 0, stream>>>(w2, w2t, HID, DIM);
    gemm1_kernel<<<dim3(HID / 128, NEXP * 64), 256, 0, stream>>>(
        xn, w1t, b1, lists, counts, bases, hbuf, 0);
    gemm2_kernel<<<dim3(DIM / 128, NEXP * 64), 256, 0, stream>>>(
        hbuf, w2t, b2, lists, wtsb, counts, bases, out, 0);
  } else {
    // sequential fallback: per-expert, reuse small buffers; bases = zeros
    __hip_bfloat16* hbuf = (__hip_bfloat16*)alloc((size_t)N_TOK * HID * 2);
    __hip_bfloat16* wt   = (__hip_bfloat16*)alloc((size_t)DIM * HID * 2);
    hipMemsetAsync(bases, 0, 256, stream);
    for (int e = 0; e < NEXP; e++) {
      transpose_cast64<<<dim3(HID / 64, DIM / 64, 1), 256, 0, stream>>>(
          w1 + (size_t)e * DIM * HID, wt, DIM, HID);
      gemm1_kernel<<<dim3(HID / 128, 64), 256, 0, stream>>>(
          xn, wt, b1, lists, counts, bases, hbuf, e);
      transpose_cast64<<<dim3(DIM / 64, HID / 64, 1), 256, 0, stream>>>(
          w2 + (size_t)e * HID * DIM, wt, HID, DIM);
      gemm2_kernel<<<dim3(DIM / 128, 64), 256, 0, stream>>>(
          hbuf, wt, b2, lists, wtsb, counts, bases, out, e);
    }
  }
}

// Round 3
// 732.539 us; speedup vs baseline: 1.7812x; 1.0517x over previous
//
#include <hip/hip_runtime.h>
#include <hip/hip_bf16.h>

#define N_TOK 8192
#define DIM   1024
#define HID   4096
#define NEXP  8
#define CSTR  64   // counts stride in ints

using bf16x8 = __attribute__((ext_vector_type(8))) short;
using f32x4  = __attribute__((ext_vector_type(4))) float;

__device__ __forceinline__ void gload_lds16(const void* g, void* l) {
  __builtin_amdgcn_global_load_lds(
      (const __attribute__((address_space(1))) unsigned int*)g,
      (__attribute__((address_space(3))) unsigned int*)l, 16, 0, 0);
}

__device__ __forceinline__ float wredsum(float v) {
#pragma unroll
  for (int off = 32; off > 0; off >>= 1) v += __shfl_xor(v, off, 64);
  return v;
}

__device__ __forceinline__ unsigned short f2bf(float f) {
  __hip_bfloat16 h = __float2bfloat16(f);
  return *reinterpret_cast<unsigned short*>(&h);
}

// ---------------- prep: LN + confidence + router + top-2 dispatch (1 wave / token) ----------------
__global__ __launch_bounds__(256) void prep_kernel(
    const float* __restrict__ x, const float* __restrict__ gamma, const float* __restrict__ beta,
    const float* __restrict__ conf_w, const float* __restrict__ conf_b,
    const float* __restrict__ rw, const float* __restrict__ rb,
    __hip_bfloat16* __restrict__ xn, float* __restrict__ out,
    int* __restrict__ counts, int* __restrict__ lists, float* __restrict__ wts) {
  const int t = blockIdx.x * 4 + (threadIdx.x >> 6);
  const int lane = threadIdx.x & 63;
  const float* xr = x + (size_t)t * DIM;

  float4 xv[4];
#pragma unroll
  for (int q = 0; q < 4; q++) xv[q] = *(const float4*)(xr + q * 256 + lane * 4);

  float s = 0.f, s2 = 0.f;
#pragma unroll
  for (int q = 0; q < 4; q++) {
    s  += xv[q].x + xv[q].y + xv[q].z + xv[q].w;
    s2 += xv[q].x * xv[q].x + xv[q].y * xv[q].y + xv[q].z * xv[q].z + xv[q].w * xv[q].w;
  }
  s = wredsum(s); s2 = wredsum(s2);
  const float mu  = s * (1.f / DIM);
  const float inv = rsqrtf(s2 * (1.f / DIM) - mu * mu + 1e-5f);

  float p[9];
#pragma unroll
  for (int e = 0; e < 9; e++) p[e] = 0.f;

#pragma unroll
  for (int q = 0; q < 4; q++) {
    const int d0 = q * 256 + lane * 4;
    const float4 g4 = *(const float4*)(gamma + d0);
    const float4 b4 = *(const float4*)(beta + d0);
    float v0 = (xv[q].x - mu) * inv * g4.x + b4.x;
    float v1 = (xv[q].y - mu) * inv * g4.y + b4.y;
    float v2 = (xv[q].z - mu) * inv * g4.z + b4.z;
    float v3 = (xv[q].w - mu) * inv * g4.w + b4.w;

    ushort4 st; st.x = f2bf(v0); st.y = f2bf(v1); st.z = f2bf(v2); st.w = f2bf(v3);
    *(ushort4*)((unsigned short*)xn + (size_t)t * DIM + d0) = st;
    *(float4*)(out + (size_t)t * DIM + d0) = xv[q];
    *(float4*)(out + (size_t)N_TOK * DIM + N_TOK + (size_t)t * DIM + d0) = xv[q];

    const float vv[4] = {v0, v1, v2, v3};
#pragma unroll
    for (int j = 0; j < 4; j++) {
      const int d = d0 + j;
      const float v = vv[j];
      p[8] += v * conf_w[d];
      const float4 r0 = *(const float4*)(rw + d * 8);
      const float4 r1 = *(const float4*)(rw + d * 8 + 4);
      p[0] += v * r0.x; p[1] += v * r0.y; p[2] += v * r0.z; p[3] += v * r0.w;
      p[4] += v * r1.x; p[5] += v * r1.y; p[6] += v * r1.z; p[7] += v * r1.w;
    }
  }
#pragma unroll
  for (int e = 0; e < 9; e++) p[e] = wredsum(p[e]);

  if (lane == 0) {
    float L[8];
#pragma unroll
    for (int e = 0; e < 8; e++) L[e] = p[e] + rb[e];
    const float cl = p[8] + conf_b[0];
    out[(size_t)N_TOK * DIM + t] = 1.f / (1.f + expf(-cl));

    float mx = L[0];
#pragma unroll
    for (int e = 1; e < 8; e++) mx = fmaxf(mx, L[e]);
    float pe[8];
#pragma unroll
    for (int e = 0; e < 8; e++) pe[e] = expf(L[e] - mx);
    int i0 = 0; float v0 = pe[0];
#pragma unroll
    for (int e = 1; e < 8; e++) if (pe[e] > v0) { v0 = pe[e]; i0 = e; }
    int i1 = -1; float v1 = -1.f;
#pragma unroll
    for (int e = 0; e < 8; e++) if (e != i0 && pe[e] > v1) { v1 = pe[e]; i1 = e; }
    const float wsum = v0 + v1;
    const float w0 = v0 / wsum, w1 = v1 / wsum;
    int p0 = atomicAdd(&counts[i0 * CSTR], 1);
    lists[i0 * N_TOK + p0] = t; wts[i0 * N_TOK + p0] = w0;
    int p1 = atomicAdd(&counts[i1 * CSTR], 1);
    lists[i1 * N_TOK + p1] = t; wts[i1 * N_TOK + p1] = w1;
  }
}

// ---------------- exclusive prefix sum of counts -> bases ----------------
__global__ void bases_kernel(const int* __restrict__ counts, int* __restrict__ bases) {
  if (threadIdx.x == 0) {
    int s = 0;
#pragma unroll
    for (int e = 0; e < NEXP; e++) { bases[e] = s; s += counts[e * CSTR]; }
  }
}

// ---------------- transpose + cast fp32[R][C] -> bf16[C][R], 64x64 tiles, z = matrix ----------------
__global__ __launch_bounds__(256) void transpose_cast64(
    const float* __restrict__ src0, __hip_bfloat16* __restrict__ dst0, int R, int C) {
  __shared__ float tile[64][65];
  const size_t msz = (size_t)R * C;
  const float* src = src0 + blockIdx.z * msz;
  __hip_bfloat16* dst = dst0 + blockIdx.z * msz;
  const int c0 = blockIdx.x * 64, r0 = blockIdx.y * 64;
  const int tid = threadIdx.x;
  const int tx = tid & 15, ty = tid >> 4;
#pragma unroll
  for (int k = 0; k < 4; k++) {
    const int row = ty + k * 16;
    const float4 v = *(const float4*)(src + (size_t)(r0 + row) * C + c0 + tx * 4);
    tile[row][tx * 4 + 0] = v.x; tile[row][tx * 4 + 1] = v.y;
    tile[row][tx * 4 + 2] = v.z; tile[row][tx * 4 + 3] = v.w;
  }
  __syncthreads();
#pragma unroll
  for (int k = 0; k < 4; k++) {
    const int orow = ty + k * 16;
    ushort4 st;
    st.x = f2bf(tile[tx * 4 + 0][orow]);
    st.y = f2bf(tile[tx * 4 + 1][orow]);
    st.z = f2bf(tile[tx * 4 + 2][orow]);
    st.w = f2bf(tile[tx * 4 + 3][orow]);
    *(ushort4*)((unsigned short*)dst + (size_t)(c0 + orow) * R + r0 + tx * 4) = st;
  }
}

// ======================= 256x256 / BK=64 counted-vmcnt GEMMs =======================
// LDS: A [2][256 rows][64 cols] bf16 at 0; B same at 64KB. chunk = 16B unit; phys
// chunk = logical_chunk ^ (row&7) (T2 swizzle, linear gload_lds dest + pre-swz src).

// ---------------- GEMM1: hbuf[base+pos] = relu(gather(xn) @ w1t^T + b1) ----------------
__global__ __launch_bounds__(512) void gemm1_kernel(
    const __hip_bfloat16* __restrict__ xn, const __hip_bfloat16* __restrict__ w1t_b,
    const float* __restrict__ b1, const int* __restrict__ lists,
    const int* __restrict__ counts, const int* __restrict__ bases,
    __hip_bfloat16* __restrict__ hbuf, const int e0) {
  const int e = e0 + (int)(blockIdx.y >> 5);
  const int rt = blockIdx.y & 31;
  const int cnt = counts[e * CSTR];
  if (rt * 256 >= cnt) return;
  const int hbase = bases[e];
  const int ct = blockIdx.x;
  const int* list = lists + e * N_TOK;
  const __hip_bfloat16* w1t = w1t_b + (size_t)(e - e0) * DIM * HID;

  __shared__ char smem[131072];
  const int tid = threadIdx.x;
  const int l = tid & 63;
  const int w = tid >> 6;
  const int wr = w >> 2;
  const int wc = w & 3;

  // staging: wave w covers rows [w*32, w*32+32) of both tiles; 4 loads each
  const int schunk = ((l & 7) ^ ((l >> 3) & 7)) * 8;  // pre-swizzled source col (elems)
  const unsigned short* srcA[4];
  const unsigned short* srcB[4];
  int ldsoff[4];
#pragma unroll
  for (int j = 0; j < 4; j++) {
    const int row = w * 32 + j * 8 + (l >> 3);
    const int pos = rt * 256 + row;
    const int tok = list[pos < cnt ? pos : 0];
    srcA[j] = (const unsigned short*)xn + (size_t)tok * DIM + schunk;
    srcB[j] = (const unsigned short*)w1t + (size_t)(ct * 256 + row) * DIM + schunk;
    ldsoff[j] = w * 4096 + j * 1024 + l * 16;
  }
  auto stage = [&](int kt, int p) {
#pragma unroll
    for (int j = 0; j < 4; j++) {
      gload_lds16(srcA[j] + kt * 64, smem + p * 32768 + ldsoff[j]);
      gload_lds16(srcB[j] + kt * 64, smem + 65536 + p * 32768 + ldsoff[j]);
    }
  };

  // fragment read offsets (bytes): row*128 + ((ks*4 + (l>>4)) ^ (l&7))*16
  const int c0 = (((l >> 4) + 0) ^ (l & 7)) << 4;
  const int c1 = (((l >> 4) + 4) ^ (l & 7)) << 4;
  const int rowAb = (wr * 128 + (l & 15)) * 128;
  const int rowBb = 65536 + (wc * 64 + (l & 15)) * 128;

  f32x4 acc[8][4] = {};
  stage(0, 0);
  const int nk = DIM / 64;
  for (int kt = 0; kt < nk; ++kt) {
    const int p = kt & 1;
    __builtin_amdgcn_s_barrier();                 // prev buffer's readers done
    if (kt + 1 < nk) {
      stage(kt + 1, p ^ 1);
      asm volatile("s_waitcnt vmcnt(8)" ::: "memory");   // kt's loads landed; kt+1 in flight
    } else {
      asm volatile("s_waitcnt vmcnt(0)" ::: "memory");
    }
    __builtin_amdgcn_s_barrier();                 // all waves' kt loads landed
    const char* Ab = smem + p * 32768 + rowAb;
    const char* Bb = smem + p * 32768 + rowBb;
    bf16x8 bf[4][2];
#pragma unroll
    for (int n = 0; n < 4; n++) {
      bf[n][0] = *(const bf16x8*)(Bb + n * 2048 + c0);
      bf[n][1] = *(const bf16x8*)(Bb + n * 2048 + c1);
    }
#pragma unroll
    for (int q = 0; q < 4; q++) {
      bf16x8 af[2][2];
#pragma unroll
      for (int mm = 0; mm < 2; mm++) {
        af[mm][0] = *(const bf16x8*)(Ab + (q * 2 + mm) * 2048 + c0);
        af[mm][1] = *(const bf16x8*)(Ab + (q * 2 + mm) * 2048 + c1);
      }
      __builtin_amdgcn_s_setprio(1);
#pragma unroll
      for (int mm = 0; mm < 2; mm++)
#pragma unroll
        for (int n = 0; n < 4; n++) {
          acc[q * 2 + mm][n] = __builtin_amdgcn_mfma_f32_16x16x32_bf16(af[mm][0], bf[n][0], acc[q * 2 + mm][n], 0, 0, 0);
          acc[q * 2 + mm][n] = __builtin_amdgcn_mfma_f32_16x16x32_bf16(af[mm][1], bf[n][1], acc[q * 2 + mm][n], 0, 0, 0);
        }
      __builtin_amdgcn_s_setprio(0);
    }
  }

#pragma unroll
  for (int n = 0; n < 4; n++) {
    const int col = ct * 256 + wc * 64 + n * 16 + (l & 15);
    const float bv = b1[e * HID + col];
#pragma unroll
    for (int m = 0; m < 8; m++) {
      f32x4 v = acc[m][n];
#pragma unroll
      for (int j = 0; j < 4; j++) {
        const int pos = rt * 256 + wr * 128 + m * 16 + (l >> 4) * 4 + j;
        if (pos < cnt)
          hbuf[(size_t)(hbase + pos) * HID + col] = __float2bfloat16(fmaxf(v[j] + bv, 0.f));
      }
    }
  }
}

// ---------------- GEMM2 (split-K x2): out[tok] += w * (hbuf @ w2t^T + b2) ----------------
__global__ __launch_bounds__(512) void gemm2_kernel(
    const __hip_bfloat16* __restrict__ hbuf, const __hip_bfloat16* __restrict__ w2t_b,
    const float* __restrict__ b2, const int* __restrict__ lists,
    const float* __restrict__ wts, const int* __restrict__ counts,
    const int* __restrict__ bases, float* __restrict__ out, const int e0) {
  const int e = e0 + (int)(blockIdx.y >> 6);
  const int rt = (int)((blockIdx.y >> 1) & 31);
  const int ksp = (int)(blockIdx.y & 1);
  const int cnt = counts[e * CSTR];
  if (rt * 256 >= cnt) return;
  const int hbase = bases[e];
  const int ct = blockIdx.x;
  const __hip_bfloat16* w2t = w2t_b + (size_t)(e - e0) * DIM * HID;
  const int kbase = ksp * (HID / 2);

  __shared__ char smem[131072];
  __shared__ int s_tok[256];
  __shared__ float s_w[256];
  const int tid = threadIdx.x;
  const int l = tid & 63;
  const int w = tid >> 6;
  const int wr = w >> 2;
  const int wc = w & 3;

  if (tid < 256) {
    const int pos = rt * 256 + tid;
    const bool vld = pos < cnt;
    s_tok[tid] = vld ? lists[e * N_TOK + pos] : -1;
    s_w[tid]  = vld ? wts[e * N_TOK + pos] : 0.f;
  }
  __syncthreads();

  const int schunk = ((l & 7) ^ ((l >> 3) & 7)) * 8;
  const unsigned short* srcA[4];
  const unsigned short* srcB[4];
  int ldsoff[4];
#pragma unroll
  for (int j = 0; j < 4; j++) {
    const int row = w * 32 + j * 8 + (l >> 3);
    srcA[j] = (const unsigned short*)hbuf + (size_t)(hbase + rt * 256 + row) * HID + kbase + schunk;
    srcB[j] = (const unsigned short*)w2t + (size_t)(ct * 256 + row) * HID + kbase + schunk;
    ldsoff[j] = w * 4096 + j * 1024 + l * 16;
  }
  auto stage = [&](int kt, int p) {
#pragma unroll
    for (int j = 0; j < 4; j++) {
      gload_lds16(srcA[j] + kt * 64, smem + p * 32768 + ldsoff[j]);
      gload_lds16(srcB[j] + kt * 64, smem + 65536 + p * 32768 + ldsoff[j]);
    }
  };

  const int c0 = (((l >> 4) + 0) ^ (l & 7)) << 4;
  const int c1 = (((l >> 4) + 4) ^ (l & 7)) << 4;
  const int rowAb = (wr * 128 + (l & 15)) * 128;
  const int rowBb = 65536 + (wc * 64 + (l & 15)) * 128;

  f32x4 acc[8][4] = {};
  stage(0, 0);
  const int nk = (HID / 2) / 64;
  for (int kt = 0; kt < nk; ++kt) {
    const int p = kt & 1;
    __builtin_amdgcn_s_barrier();
    if (kt + 1 < nk) {
      stage(kt + 1, p ^ 1);
      asm volatile("s_waitcnt vmcnt(8)" ::: "memory");
    } else {
      asm volatile("s_waitcnt vmcnt(0)" ::: "memory");
    }
    __builtin_amdgcn_s_barrier();
    const char* Ab = smem + p * 32768 + rowAb;
    const char* Bb = smem + p * 32768 + rowBb;
    bf16x8 bf[4][2];
#pragma unroll
    for (int n = 0; n < 4; n++) {
      bf[n][0] = *(const bf16x8*)(Bb + n * 2048 + c0);
      bf[n][1] = *(const bf16x8*)(Bb + n * 2048 + c1);
    }
#pragma unroll
    for (int q = 0; q < 4; q++) {
      bf16x8 af[2][2];
#pragma unroll
      for (int mm = 0; mm < 2; mm++) {
        af[mm][0] = *(const bf16x8*)(Ab + (q * 2 + mm) * 2048 + c0);
        af[mm][1] = *(const bf16x8*)(Ab + (q * 2 + mm) * 2048 + c1);
      }
      __builtin_amdgcn_s_setprio(1);
#pragma unroll
      for (int mm = 0; mm < 2; mm++)
#pragma unroll
        for (int n = 0; n < 4; n++) {
          acc[q * 2 + mm][n] = __builtin_amdgcn_mfma_f32_16x16x32_bf16(af[mm][0], bf[n][0], acc[q * 2 + mm][n], 0, 0, 0);
          acc[q * 2 + mm][n] = __builtin_amdgcn_mfma_f32_16x16x32_bf16(af[mm][1], bf[n][1], acc[q * 2 + mm][n], 0, 0, 0);
        }
      __builtin_amdgcn_s_setprio(0);
    }
  }

#pragma unroll
  for (int n = 0; n < 4; n++) {
    const int col = ct * 256 + wc * 64 + n * 16 + (l & 15);
    const float bv = (ksp == 0) ? b2[e * DIM + col] : 0.f;
#pragma unroll
    for (int m = 0; m < 8; m++) {
      f32x4 v = acc[m][n];
#pragma unroll
      for (int j = 0; j < 4; j++) {
        const int rowi = wr * 128 + m * 16 + (l >> 4) * 4 + j;
        const int tok = s_tok[rowi];
        if (tok >= 0)
          unsafeAtomicAdd(out + (size_t)tok * DIM + col, s_w[rowi] * (v[j] + bv));
      }
    }
  }
}

extern "C" void kernel_launch(void* const* d_in, const int* in_sizes, int n_in,
                              void* d_out, int out_size, void* d_ws, size_t ws_size,
                              hipStream_t stream) {
  (void)in_sizes; (void)n_in; (void)out_size;
  const float* x      = (const float*)d_in[0];
  const float* gamma  = (const float*)d_in[1];
  const float* beta   = (const float*)d_in[2];
  const float* conf_w = (const float*)d_in[3];
  const float* conf_b = (const float*)d_in[4];
  const float* rw     = (const float*)d_in[5];
  const float* rb     = (const float*)d_in[6];
  const float* w1     = (const float*)d_in[7];
  const float* b1     = (const float*)d_in[8];
  const float* w2     = (const float*)d_in[9];
  const float* b2     = (const float*)d_in[10];
  float* out = (float*)d_out;

  char* w = (char*)d_ws;
  auto alloc = [&](size_t bytes) { char* p = w; w += (bytes + 255) & ~255ULL; return p; };

  __hip_bfloat16* xn = (__hip_bfloat16*)alloc((size_t)N_TOK * DIM * 2);
  int*   lists  = (int*)alloc((size_t)NEXP * N_TOK * 4);
  float* wtsb   = (float*)alloc((size_t)NEXP * N_TOK * 4);
  int*   counts = (int*)alloc(NEXP * CSTR * 4);
  int*   bases  = (int*)alloc(256);
  size_t common = (size_t)(w - (char*)d_ws);

  const size_t hbufA = (size_t)(2 * N_TOK + 512) * HID * 2;
  const size_t wtA   = (size_t)NEXP * DIM * HID * 2;
  const bool planA = ws_size >= common + hbufA + 2 * wtA + 4096;

  hipMemsetAsync(counts, 0, NEXP * CSTR * 4, stream);
  prep_kernel<<<N_TOK / 4, 256, 0, stream>>>(x, gamma, beta, conf_w, conf_b, rw, rb,
                                             xn, out, counts, lists, wtsb);

  if (planA) {
    __hip_bfloat16* hbuf = (__hip_bfloat16*)alloc(hbufA);
    __hip_bfloat16* w1t  = (__hip_bfloat16*)alloc(wtA);
    __hip_bfloat16* w2t  = (__hip_bfloat16*)alloc(wtA);
    bases_kernel<<<1, 64, 0, stream>>>(counts, bases);
    transpose_cast64<<<dim3(HID / 64, DIM / 64, NEXP), 256, 0, stream>>>(w1, w1t, DIM, HID);
    transpose_cast64<<<dim3(DIM / 64, HID / 64, NEXP), 256, 0, stream>>>(w2, w2t, HID, DIM);
    gemm1_kernel<<<dim3(HID / 256, NEXP * 32), 512, 0, stream>>>(
        xn, w1t, b1, lists, counts, bases, hbuf, 0);
    gemm2_kernel<<<dim3(DIM / 256, NEXP * 64), 512, 0, stream>>>(
        hbuf, w2t, b2, lists, wtsb, counts, bases, out, 0);
  } else {
    __hip_bfloat16* hbuf = (__hip_bfloat16*)alloc((size_t)(N_TOK + 512) * HID * 2);
    __hip_bfloat16* wt   = (__hip_bfloat16*)alloc((size_t)DIM * HID * 2);
    hipMemsetAsync(bases, 0, 256, stream);
    for (int e = 0; e < NEXP; e++) {
      transpose_cast64<<<dim3(HID / 64, DIM / 64, 1), 256, 0, stream>>>(
          w1 + (size_t)e * DIM * HID, wt, DIM, HID);
      gemm1_kernel<<<dim3(HID / 256, 32), 512, 0, stream>>>(
          xn, wt, b1, lists, counts, bases, hbuf, e);
      transpose_cast64<<<dim3(DIM / 64, HID / 64, 1), 256, 0, stream>>>(
          w2 + (size_t)e * HID * DIM, wt, HID, DIM);
      gemm2_kernel<<<dim3(DIM / 256, 64), 512, 0, stream>>>(
          hbuf, wt, b2, lists, wtsb, counts, bases, out, e);
    }
  }
}